// Round 1
// baseline (278.485 us; speedup 1.0000x reference)
//
#include <hip/hip_runtime.h>
#include <stdint.h>

#define KNN 16

// Map float to a uint32 whose unsigned order matches the float order
// (handles tiny negative dists from fp rounding).
__device__ __forceinline__ uint32_t fkey(float f) {
    uint32_t u = __float_as_uint(f);
    return (u & 0x80000000u) ? ~u : (u | 0x80000000u);
}

// One wave per query. Each lane scans refs lane, lane+64, ... keeping a
// sorted (ascending) top-16 in registers; then a 16-round wave-wide u64-min
// merge reproduces jax.lax.top_k ordering exactly (dist asc, idx asc on tie).
__global__ __launch_bounds__(256) void knn_kernel(
    const float* __restrict__ xyz_prev, const float* __restrict__ xyz_cur,
    int* __restrict__ knn_idx, int n_prev, int n_cur)
{
    __shared__ unsigned long long lds[4 * 64 * KNN];  // per-lane spill area (own-lane only)
    const int wave = threadIdx.x >> 6;
    const int lane = threadIdx.x & 63;
    const int q = blockIdx.x * 4 + wave;
    if (q >= n_cur) return;  // wave-uniform exit, no __syncthreads in kernel

    const float qx = xyz_cur[3 * q + 0];
    const float qy = xyz_cur[3 * q + 1];
    const float qz = xyz_cur[3 * q + 2];
    // Mirror reference fp32 op order; q2 is a per-query constant (can't change argsort)
    const float q2 = __fadd_rn(__fadd_rn(__fmul_rn(qx, qx), __fmul_rn(qy, qy)),
                               __fmul_rn(qz, qz));

    float d[KNN];
    int   id[KNN];
#pragma unroll
    for (int j = 0; j < KNN; ++j) { d[j] = 3.4e38f; id[j] = 0x7fffffff; }

    for (int r = lane; r < n_prev; r += 64) {
        const float rx = xyz_prev[3 * r + 0];
        const float ry = xyz_prev[3 * r + 1];
        const float rz = xyz_prev[3 * r + 2];
        const float r2 = __fadd_rn(__fadd_rn(__fmul_rn(rx, rx), __fmul_rn(ry, ry)),
                                   __fmul_rn(rz, rz));
        // Eigen/XLA-style fma accumulation chain for the dot product
        const float cr = __fmaf_rn(rz, qz, __fmaf_rn(ry, qy, __fmul_rn(rx, qx)));
        const float dist = __fsub_rn(__fadd_rn(q2, r2), __fmul_rn(2.0f, cr));

        if (dist < d[KNN - 1]) {  // strict: equal dist keeps earlier (lower) idx
            d[KNN - 1] = dist;
            id[KNN - 1] = r;
            // bubble the new tail element up to its place (branch-free swaps,
            // strict < so it lands AFTER equal-dist earlier-idx entries)
#pragma unroll
            for (int j = KNN - 1; j >= 1; --j) {
                const float dj = d[j], djm = d[j - 1];
                const int   ij = id[j], ijm = id[j - 1];
                const bool sw = dj < djm;
                d[j - 1]  = sw ? dj : djm;
                d[j]      = sw ? djm : dj;
                id[j - 1] = sw ? ij : ijm;
                id[j]     = sw ? ijm : ij;
            }
        }
    }

    // Spill own sorted list to LDS so the head pointer can be a dynamic index.
    unsigned long long* my = &lds[(size_t)(wave * 64 + lane) * KNN];
#pragma unroll
    for (int j = 0; j < KNN; ++j)
        my[j] = ((unsigned long long)fkey(d[j]) << 32) | (uint32_t)id[j];

    // 16 rounds: wave-wide min of the 64 list heads. Keys are unique (ref idx
    // appears in exactly one lane), so exactly one lane advances per round.
    int head = 0;
    unsigned long long res = 0;
    for (int rr = 0; rr < KNN; ++rr) {
        const unsigned long long k = my[head];
        unsigned long long m = k;
#pragma unroll
        for (int s = 1; s < 64; s <<= 1) {
            const unsigned long long o = __shfl_xor(m, s, 64);
            m = (o < m) ? o : m;
        }
        if (k == m) ++head;
        if (lane == rr) res = m;
    }
    if (lane < KNN)
        knn_idx[q * KNN + lane] = (int)(res & 0xffffffffu);
}

// One wave per output row (q, j). C=256 -> 64 float4 per half-row: exactly one
// float4 load/store pair per lane. out[row] = [prev[idx]-cur[q], cur[q]].
__global__ __launch_bounds__(256) void combine_kernel(
    const float* __restrict__ feat_prev, const float* __restrict__ feat_cur,
    const int* __restrict__ knn_idx, float* __restrict__ out,
    int n_rows, int c4)
{
    const int wrow = blockIdx.x * 4 + (threadIdx.x >> 6);
    const int lane = threadIdx.x & 63;
    if (wrow >= n_rows) return;
    const int q  = wrow / KNN;
    const int nb = knn_idx[wrow];

    const float4* prow = (const float4*)feat_prev + (size_t)nb * c4;
    const float4* crow = (const float4*)feat_cur + (size_t)q * c4;
    float4* orow = (float4*)out + (size_t)wrow * (2 * c4);

    for (int i = lane; i < c4; i += 64) {
        const float4 p = prow[i];
        const float4 c = crow[i];
        float4 dd;
        dd.x = p.x - c.x;
        dd.y = p.y - c.y;
        dd.z = p.z - c.z;
        dd.w = p.w - c.w;
        orow[i]      = dd;
        orow[c4 + i] = c;
    }
}

extern "C" void kernel_launch(void* const* d_in, const int* in_sizes, int n_in,
                              void* d_out, int out_size, void* d_ws, size_t ws_size,
                              hipStream_t stream) {
    const float* xyz_prev  = (const float*)d_in[0];
    const float* xyz_cur   = (const float*)d_in[1];
    const float* feat_prev = (const float*)d_in[2];
    const float* feat_cur  = (const float*)d_in[3];
    float* out = (float*)d_out;

    const int n_prev = in_sizes[0] / 3;
    const int n_cur  = in_sizes[1] / 3;
    const int C      = in_sizes[2] / n_prev;   // 256

    int* knn = (int*)d_ws;                     // n_cur*KNN*4 = 256 KB scratch

    const int knn_blocks = (n_cur + 3) / 4;    // 4 waves (queries) per block
    knn_kernel<<<knn_blocks, 256, 0, stream>>>(xyz_prev, xyz_cur, knn, n_prev, n_cur);

    const int n_rows = n_cur * KNN;
    const int cmb_blocks = (n_rows + 3) / 4;   // 4 waves (rows) per block
    combine_kernel<<<cmb_blocks, 256, 0, stream>>>(feat_prev, feat_cur, knn, out,
                                                   n_rows, C / 4);
}